// Round 5
// baseline (699.714 us; speedup 1.0000x reference)
//
#include <hip/hip_runtime.h>

namespace {

constexpr int kN = 2048;
constexpr int kWords = kN / 64;   // 32
constexpr int kC1 = 256;          // HEADS*HID
constexpr int kC2 = 64;           // OUT_CH
constexpr int kIN = 512;
constexpr float kNegSlope = 0.2f;
constexpr float kLnEps = 1e-5f;

__device__ __forceinline__ float leakyf(float v) {
  return v >= 0.f ? v : kNegSlope * v;
}
// online softmax accumulate (masked stream)
__device__ __forceinline__ void onl(float& m, float& l, float v) {
  if (v > m) { l = l * __expf(m - v) + 1.f; m = v; }
  else       { l += __expf(v - m); }
}
__device__ __forceinline__ void mergeml(float& M, float& L, float m, float l) {
  if (m > M) { L = L * __expf(M - m) + l; M = m; }
  else       { L += l * __expf(m - M); }
}

// ---------------- adjacency bitsets ----------------
__global__ void build_bits(const int* __restrict__ ei, int E,
                           unsigned long long* rowbits, unsigned long long* colbitsT) {
  int e = blockIdx.x * 256 + threadIdx.x;
  if (e >= E) return;
  int s = ei[e], d = ei[E + e];
  atomicOr(&rowbits[(size_t)s * kWords + (d >> 6)], 1ull << (d & 63));
  atomicOr(&colbitsT[(size_t)(s >> 6) * kN + d], 1ull << (s & 63));
}

// Fused per-row: A2 row s (counts) -> A2 structure (colbits2T) -> A3 row s
// = sum_k A2[s][k] * rowA[k]  -> normalized motif row.  One block per s.
__global__ __launch_bounds__(256) void a3_motif(
    const unsigned long long* __restrict__ rowbits,
    float* __restrict__ motif,
    unsigned long long* __restrict__ colbits2T) {
  int s = blockIdx.x;
  int t = threadIdx.x;
  int lane = t & 63;
  __shared__ int cnt[kN];            // A2[s][k] counts (8 KB)
  __shared__ unsigned short list[kN]; // jlist (phase1) then klist (phase3)
  __shared__ int n_total;
  __shared__ float redv[4];
  // zero cnt
  reinterpret_cast<uint4*>(cnt)[t] = make_uint4(0u, 0u, 0u, 0u);
  reinterpret_cast<uint4*>(cnt)[t + 256] = make_uint4(0u, 0u, 0u, 0u);
  __syncthreads();
  // decode out-neighbors j of s (wave 0) into list
  if (t < 64) {
    unsigned long long word = (lane < kWords) ? rowbits[(size_t)s * kWords + lane] : 0ull;
    int c = __popcll(word);
    int inc = c;
    for (int o = 1; o < 64; o <<= 1) { int v = __shfl_up(inc, o); if (lane >= o) inc += v; }
    if (lane == 63) n_total = inc;
    int off = inc - c;
    int base = lane * 64;
    while (word) {
      int b = __builtin_ctzll(word);
      word &= word - 1;
      list[off++] = (unsigned short)(base + b);
    }
  }
  __syncthreads();
  int jtot = n_total;
  // phase 1: cnt[k] += 1 for each j in rowA[s], k in rowA[j]
  for (int idx = t; idx < jtot * kWords; idx += 256) {
    int j = list[idx >> 5];
    int w = idx & (kWords - 1);
    unsigned long long word = rowbits[(size_t)j * kWords + w];
    int base = w * 64;
    while (word) {
      int b = __builtin_ctzll(word);
      word &= word - 1;
      atomicAdd(&cnt[base + b], 1);
    }
  }
  __syncthreads();
  // phase 2: klist = {k: cnt[k] > 0}; also write A2 structure bit (s, k)
  if (t < 64) {
    int base = lane * 32;
    unsigned int m = 0;
#pragma unroll
    for (int i = 0; i < 32; ++i) m |= (cnt[base + i] != 0 ? 1u : 0u) << i;
    int c = __popc(m);
    int inc = c;
    for (int o = 1; o < 64; o <<= 1) { int v = __shfl_up(inc, o); if (lane >= o) inc += v; }
    if (lane == 63) n_total = inc;
    int off = inc - c;
    unsigned int mm = m;
    while (mm) {
      int b = __builtin_ctz(mm);
      mm &= mm - 1;
      int k = base + b;
      list[off++] = (unsigned short)k;
      atomicOr(&colbits2T[(size_t)(s >> 6) * kN + k], 1ull << (s & 63));
    }
  }
  __syncthreads();
  int ktot = n_total;
  // phase 3: sums[d] = sum_{k in klist} cnt[k] * A[k][d]
  int sums[8] = {};
  for (int ki = 0; ki < ktot; ++ki) {
    int k = list[ki];
    int ck = cnt[k];
    const unsigned long long* rbk = rowbits + (size_t)k * kWords;
#pragma unroll
    for (int c = 0; c < 8; ++c) {
      int d = t + c * 256;
      unsigned long long wv = rbk[d >> 6];
      if ((wv >> (d & 63)) & 1ull) sums[c] += ck;
    }
  }
  float tot = 0.f;
#pragma unroll
  for (int c = 0; c < 8; ++c) tot += (float)sums[c];
  for (int o = 32; o; o >>= 1) tot += __shfl_xor(tot, o);
  if (lane == 0) redv[t >> 6] = tot;
  __syncthreads();
  float inv = 1.f / fmaxf(redv[0] + redv[1] + redv[2] + redv[3], 1.f);
#pragma unroll
  for (int c = 0; c < 8; ++c)
    motif[(size_t)s * kN + t + c * 256] = (float)sums[c] * inv;
}

// C[z][M,Nn] = A[M,K] @ B_z[K,Nn]; B_z = z<nmain ? Bmain+z*K*Nn : Bx
__global__ __launch_bounds__(256) void gemm_batched(
    const float* __restrict__ A, const float* __restrict__ Bmain,
    const float* __restrict__ Bx, float* __restrict__ C,
    int M, int Nn, int K, int nmain) {
  int z = blockIdx.z;
  const float* B = (z < nmain) ? Bmain + (size_t)z * K * Nn : Bx;
  float* Cz = C + (size_t)z * M * Nn;
  __shared__ float As[16][65];
  __shared__ float Bs[16][65];
  int t = threadIdx.x;
  int tx = t & 15, ty = t >> 4;
  int row0 = blockIdx.y * 64, col0 = blockIdx.x * 64;
  float acc[4][4] = {};
  for (int k0 = 0; k0 < K; k0 += 16) {
    {
      int e = t * 4;
      int m = e >> 4, kk = e & 15;
      float4 va = *reinterpret_cast<const float4*>(A + (size_t)(row0 + m) * K + k0 + kk);
      As[kk + 0][m] = va.x; As[kk + 1][m] = va.y;
      As[kk + 2][m] = va.z; As[kk + 3][m] = va.w;
    }
    {
      int kb = t >> 4, nb = (t & 15) * 4;
      float4 vb = *reinterpret_cast<const float4*>(B + (size_t)(k0 + kb) * Nn + col0 + nb);
      Bs[kb][nb + 0] = vb.x; Bs[kb][nb + 1] = vb.y;
      Bs[kb][nb + 2] = vb.z; Bs[kb][nb + 3] = vb.w;
    }
    __syncthreads();
#pragma unroll
    for (int kk2 = 0; kk2 < 16; ++kk2) {
      float a[4], b[4];
#pragma unroll
      for (int i = 0; i < 4; ++i) a[i] = As[kk2][ty * 4 + i];
#pragma unroll
      for (int j = 0; j < 4; ++j) b[j] = Bs[kk2][tx * 4 + j];
#pragma unroll
      for (int i = 0; i < 4; ++i)
#pragma unroll
        for (int j = 0; j < 4; ++j) acc[i][j] += a[i] * b[j];
    }
    __syncthreads();
  }
  for (int i = 0; i < 4; ++i)
    for (int j = 0; j < 4; ++j)
      Cz[(size_t)(row0 + ty * 4 + i) * Nn + col0 + tx * 4 + j] = acc[i][j];
}

// s_src[hop,n,h], s_dst[hop,n,h]; block = H*64 threads; grid (N, 2)
template <int H>
__global__ void src_dst(const float* __restrict__ hopx,
                        const float* __restrict__ att_s,
                        const float* __restrict__ att_d,
                        float* __restrict__ ssrc, float* __restrict__ sdst) {
  int hop = blockIdx.y;
  int n = blockIdx.x;
  int t = threadIdx.x;
  int hh = t >> 6, c = t & 63;
  float xv = hopx[((size_t)hop * kN + n) * (H * 64) + t];
  float ps = xv * att_s[hop * H * 64 + hh * 64 + c];
  float pd = xv * att_d[hop * H * 64 + hh * 64 + c];
  for (int o = 32; o; o >>= 1) { ps += __shfl_xor(ps, o); pd += __shfl_xor(pd, o); }
  if (c == 0) {
    ssrc[((size_t)hop * kN + n) * H + hh] = ps;
    sdst[((size_t)hop * kN + n) * H + hh] = pd;
  }
}

// per (d,h): online-softmax stats over set bits of column mask.
// One wave per dst; lane l owns half of word l>>1. block 256; grid (N/4, 2)
template <int H>
__global__ __launch_bounds__(256) void stats_bits(
    const float* __restrict__ ssrc, const float* __restrict__ sdst,
    const float* __restrict__ motif,
    const unsigned long long* __restrict__ colbitsT,
    const unsigned long long* __restrict__ colbits2T,
    float* __restrict__ stats) {
  int hop = blockIdx.y;
  const unsigned long long* colmaskT = hop ? colbits2T : colbitsT;
  ssrc += (size_t)hop * kN * H;
  sdst += (size_t)hop * kN * H;
  stats += (size_t)hop * kN * H * 4;
  int wave = threadIdx.x >> 6, lane = threadIdx.x & 63;
  int d = blockIdx.x * 4 + wave;
  int w = lane >> 1, half = lane & 1;
  unsigned long long word = colmaskT[(size_t)w * kN + d];
  if (w == (d >> 6)) word |= 1ull << (d & 63);  // diagonal always masked-in
  unsigned int bits = (unsigned int)(word >> (half * 32));
  float sd[H];
#pragma unroll
  for (int h = 0; h < H; ++h) sd[h] = sdst[d * H + h];
  float m1[H], l1[H], m2[H], l2[H];
#pragma unroll
  for (int h = 0; h < H; ++h) { m1[h] = m2[h] = -3.0e38f; l1[h] = l2[h] = 0.f; }
  int base = w * 64 + half * 32;
  while (bits) {
    int b = __builtin_ctz(bits);
    bits &= bits - 1;
    int s = base + b;
    float mv = motif[(size_t)s * kN + d];
#pragma unroll
    for (int h = 0; h < H; ++h) {
      float v = ssrc[s * H + h] + sd[h];
      onl(m1[h], l1[h], leakyf(v));
      onl(m2[h], l2[h], leakyf(v * mv));
    }
  }
#pragma unroll
  for (int o = 1; o < 64; o <<= 1) {
#pragma unroll
    for (int h = 0; h < H; ++h) {
      float mm = __shfl_xor(m1[h], o), ll = __shfl_xor(l1[h], o);
      mergeml(m1[h], l1[h], mm, ll);
      float mm2 = __shfl_xor(m2[h], o), ll2 = __shfl_xor(l2[h], o);
      mergeml(m2[h], l2[h], mm2, ll2);
    }
  }
  if (lane == 0) {
#pragma unroll
    for (int h = 0; h < H; ++h) {
      float* sp = stats + ((size_t)d * H + h) * 4;
      sp[0] = m1[h]; sp[1] = 1.f / l1[h]; sp[2] = m2[h]; sp[3] = 1.f / l2[h];
    }
  }
}

// layer-1 aggregation: one dst per block (256 thr = 256 channels), both hops,
// sparse s-list from bitsets; fused bias + ELU. grid = N.
__global__ __launch_bounds__(256) void agg_l1(
    const float* __restrict__ hx,      // [2][N][256]
    const float* __restrict__ ssrc,    // [2][N][4]
    const float* __restrict__ sdst,    // [2][N][4]
    const float* __restrict__ motif,
    const unsigned long long* __restrict__ colbitsT,
    const unsigned long long* __restrict__ colbits2T,
    const float* __restrict__ stats,   // [2][N][4][4]
    const float* __restrict__ hop_att,
    const float* __restrict__ bias,
    float* __restrict__ hbuf) {
  int d = blockIdx.x;
  int t = threadIdx.x;
  int lane = t & 63;
  int h = t >> 6;
  __shared__ unsigned short slist[kN];
  __shared__ float w_lds[64 * 4];
  __shared__ int s_total;
  float a0 = hop_att[0], a1 = hop_att[1];
  float mxa = fmaxf(a0, a1);
  float e0 = __expf(a0 - mxa), e1 = __expf(a1 - mxa);
  float wh0 = e0 / (e0 + e1), wh1 = e1 / (e0 + e1);
  float acc = 0.f;
  for (int hop = 0; hop < 2; ++hop) {
    const unsigned long long* cm = hop ? colbits2T : colbitsT;
    if (t < 64) {
      unsigned long long word = (lane < kWords) ? cm[(size_t)lane * kN + d] : 0ull;
      if (lane == (d >> 6)) word |= 1ull << (d & 63);
      int cnt = __popcll(word);
      int inc = cnt;
      for (int o = 1; o < 64; o <<= 1) { int v = __shfl_up(inc, o); if (lane >= o) inc += v; }
      if (lane == 63) s_total = inc;
      int off = inc - cnt;
      int base = lane * 64;
      while (word) {
        int b = __builtin_ctzll(word);
        word &= word - 1;
        slist[off++] = (unsigned short)(base + b);
      }
    }
    __syncthreads();
    int total = s_total;
    float sd = sdst[((size_t)hop * kN + d) * 4 + h];
    const float* sp = &stats[(((size_t)hop * kN + d) * 4 + h) * 4];
    float m1 = sp[0], il1 = sp[1], m2 = sp[2], il2 = sp[3];
    float wh = hop ? wh1 : wh0;
    const float* hxp = hx + (size_t)hop * kN * kC1;
    const float* ssp = ssrc + (size_t)hop * kN * 4;
    for (int c0 = 0; c0 < total; c0 += 64) {
      int nsi = min(64, total - c0);
      int si = lane;
      if (si < nsi) {
        int s = slist[c0 + si];
        float mv = motif[(size_t)s * kN + d];
        float v = ssp[s * 4 + h] + sd;
        w_lds[si * 4 + h] = (0.5f * __expf(leakyf(v) - m1) * il1 +
                             0.5f * __expf(leakyf(v * mv) - m2) * il2) * wh;
      }
      __syncthreads();
      for (int q = 0; q < nsi; ++q) {
        int s = slist[c0 + q];
        acc += w_lds[q * 4 + h] * hxp[(size_t)s * kC1 + t];
      }
      __syncthreads();
    }
    __syncthreads();
  }
  acc += bias[t];
  hbuf[(size_t)d * kC1 + t] = acc > 0.f ? acc : __expf(acc) - 1.f;
}

// layer-2 aggregation: one dst per block, 4 si-subgroups x 64 channels;
// fused residual + LayerNorm + bias -> final output. grid = N.
__global__ __launch_bounds__(256) void agg_l2(
    const float* __restrict__ hx,      // [2][N][64]
    const float* __restrict__ ssrc,    // [2][N]
    const float* __restrict__ sdst,    // [2][N]
    const float* __restrict__ motif,
    const unsigned long long* __restrict__ colbitsT,
    const unsigned long long* __restrict__ colbits2T,
    const float* __restrict__ stats,   // [2][N][4]
    const float* __restrict__ hop_att,
    const float* __restrict__ res,     // [N][64]
    const float* __restrict__ lns, const float* __restrict__ lnb,
    const float* __restrict__ l2b,
    float* __restrict__ out) {
  int d = blockIdx.x;
  int t = threadIdx.x;
  int lane = t & 63;   // channel
  int g = t >> 6;      // si-subgroup
  __shared__ unsigned short slist[kN];
  __shared__ float w_lds[64];
  __shared__ int s_total;
  __shared__ float red[4][64];
  float a0 = hop_att[0], a1 = hop_att[1];
  float mxa = fmaxf(a0, a1);
  float e0 = __expf(a0 - mxa), e1 = __expf(a1 - mxa);
  float wh0 = e0 / (e0 + e1), wh1 = e1 / (e0 + e1);
  float acc = 0.f;
  for (int hop = 0; hop < 2; ++hop) {
    const unsigned long long* cm = hop ? colbits2T : colbitsT;
    if (t < 64) {
      unsigned long long word = (lane < kWords) ? cm[(size_t)lane * kN + d] : 0ull;
      if (lane == (d >> 6)) word |= 1ull << (d & 63);
      int cnt = __popcll(word);
      int inc = cnt;
      for (int o = 1; o < 64; o <<= 1) { int v = __shfl_up(inc, o); if (lane >= o) inc += v; }
      if (lane == 63) s_total = inc;
      int off = inc - cnt;
      int base = lane * 64;
      while (word) {
        int b = __builtin_ctzll(word);
        word &= word - 1;
        slist[off++] = (unsigned short)(base + b);
      }
    }
    __syncthreads();
    int total = s_total;
    float sd = sdst[(size_t)hop * kN + d];
    const float* sp = &stats[((size_t)hop * kN + d) * 4];
    float m1 = sp[0], il1 = sp[1], m2 = sp[2], il2 = sp[3];
    float wh = hop ? wh1 : wh0;
    const float* hxp = hx + (size_t)hop * kN * kC2;
    const float* ssp = ssrc + (size_t)hop * kN;
    for (int c0 = 0; c0 < total; c0 += 64) {
      int nsi = min(64, total - c0);
      if (t < nsi) {
        int s = slist[c0 + t];
        float mv = motif[(size_t)s * kN + d];
        float v = ssp[s] + sd;
        w_lds[t] = (0.5f * __expf(leakyf(v) - m1) * il1 +
                    0.5f * __expf(leakyf(v * mv) - m2) * il2) * wh;
      }
      __syncthreads();
      for (int q = g; q < nsi; q += 4) {
        int s = slist[c0 + q];
        acc += w_lds[q] * hxp[(size_t)s * kC2 + lane];
      }
      __syncthreads();
    }
    __syncthreads();
  }
  red[g][lane] = acc;
  __syncthreads();
  if (t < 64) {
    float v = red[0][t] + red[1][t] + red[2][t] + red[3][t] + res[(size_t)d * kC2 + t];
    float s = v;
    for (int o = 32; o; o >>= 1) s += __shfl_xor(s, o);
    float mu = s * (1.f / kC2);
    float dv = v - mu;
    float q = dv * dv;
    for (int o = 32; o; o >>= 1) q += __shfl_xor(q, o);
    float var = q * (1.f / kC2);
    out[(size_t)d * kC2 + t] = dv * rsqrtf(var + kLnEps) * lns[t] + lnb[t] + l2b[t];
  }
}

}  // namespace

extern "C" void kernel_launch(void* const* d_in, const int* in_sizes, int n_in,
                              void* d_out, int out_size, void* d_ws, size_t ws_size,
                              hipStream_t stream) {
  const float* x    = (const float*)d_in[0];
  const int*   ei   = (const int*)d_in[1];
  const float* l1w  = (const float*)d_in[2];
  const float* l1as = (const float*)d_in[3];
  const float* l1ad = (const float*)d_in[4];
  const float* l1ha = (const float*)d_in[5];
  const float* l1b  = (const float*)d_in[6];
  const float* l2w  = (const float*)d_in[7];
  const float* l2as = (const float*)d_in[8];
  const float* l2ad = (const float*)d_in[9];
  const float* l2ha = (const float*)d_in[10];
  const float* l2rw = (const float*)d_in[11];
  const float* lns  = (const float*)d_in[12];
  const float* lnb  = (const float*)d_in[13];
  const float* l2b  = (const float*)d_in[14];
  int E = in_sizes[1] / 2;

  // ---- workspace layout (bytes) ----
  size_t o = 0;
  auto take = [&](size_t bytes) { size_t r = o; o += (bytes + 255) & ~(size_t)255; return r; };
  size_t oRB  = take((size_t)kN * kWords * 8);      // rowbits
  size_t oCB  = take((size_t)kWords * kN * 8);      // colbitsT
  size_t oCB2 = take((size_t)kWords * kN * 8);      // colbits2T (A2 structure)
  size_t zEnd = o;                                  // zero region end
  size_t oMF  = take((size_t)kN * kN * 4);
  size_t oHX1 = take((size_t)2 * kN * kC1 * 4);
  size_t oH   = take((size_t)kN * kC1 * 4);
  size_t oHX2 = take((size_t)3 * kN * kC2 * 4);     // hop0 | hop1 | res
  size_t oSS1 = take((size_t)2 * kN * 4 * 4);
  size_t oSD1 = take((size_t)2 * kN * 4 * 4);
  size_t oSS2 = take((size_t)2 * kN * 4);
  size_t oSD2 = take((size_t)2 * kN * 4);
  size_t oST1 = take((size_t)2 * kN * 4 * 4 * 4);
  size_t oST2 = take((size_t)2 * kN * 4 * 4);
  if (ws_size < o) return;  // insufficient scratch; fail visibly

  char* w = (char*)d_ws;
  unsigned long long* rowbits = (unsigned long long*)(w + oRB);
  unsigned long long* colbitsT = (unsigned long long*)(w + oCB);
  unsigned long long* colbits2T = (unsigned long long*)(w + oCB2);
  float* motif = (float*)(w + oMF);
  float* hx1 = (float*)(w + oHX1);
  float* hbuf = (float*)(w + oH);
  float* hx2 = (float*)(w + oHX2);
  float* res = hx2 + (size_t)2 * kN * kC2;
  float* ss1 = (float*)(w + oSS1);
  float* sd1 = (float*)(w + oSD1);
  float* ss2 = (float*)(w + oSS2);
  float* sd2 = (float*)(w + oSD2);
  float* st1 = (float*)(w + oST1);
  float* st2 = (float*)(w + oST2);

  hipMemsetAsync(d_ws, 0, zEnd, stream);

  build_bits<<<(E + 255) / 256, 256, 0, stream>>>(ei, E, rowbits, colbitsT);
  a3_motif<<<kN, 256, 0, stream>>>(rowbits, motif, colbits2T);

  // ---- layer 1 (H=4, C=64, concat) ----
  gemm_batched<<<dim3(kC1 / 64, kN / 64, 2), 256, 0, stream>>>(
      x, l1w, l1w, hx1, kN, kC1, kIN, 2);
  src_dst<4><<<dim3(kN, 2), 256, 0, stream>>>(hx1, l1as, l1ad, ss1, sd1);
  stats_bits<4><<<dim3(kN / 4, 2), 256, 0, stream>>>(
      ss1, sd1, motif, colbitsT, colbits2T, st1);
  agg_l1<<<kN, 256, 0, stream>>>(hx1, ss1, sd1, motif, colbitsT, colbits2T,
                                 st1, l1ha, l1b, hbuf);

  // ---- layer 2 (H=1, C=64, residual + LN) ----
  gemm_batched<<<dim3(1, kN / 64, 3), 256, 0, stream>>>(
      hbuf, l2w, l2rw, hx2, kN, kC2, kC1, 2);
  src_dst<1><<<dim3(kN, 2), 64, 0, stream>>>(hx2, l2as, l2ad, ss2, sd2);
  stats_bits<1><<<dim3(kN / 4, 2), 256, 0, stream>>>(
      ss2, sd2, motif, colbitsT, colbits2T, st2);
  agg_l2<<<kN, 256, 0, stream>>>(hx2, ss2, sd2, motif, colbitsT, colbits2T,
                                 st2, l2ha, res, lns, lnb, l2b, (float*)d_out);
}

// Round 6
// 241.712 us; speedup vs baseline: 2.8948x; 2.8948x over previous
//
#include <hip/hip_runtime.h>

namespace {

constexpr int kN = 2048;
constexpr int kWords = kN / 64;   // 32
constexpr int kC1 = 256;          // HEADS*HID
constexpr int kC2 = 64;           // OUT_CH
constexpr int kIN = 512;
constexpr float kNegSlope = 0.2f;
constexpr float kLnEps = 1e-5f;

__device__ __forceinline__ float leakyf(float v) {
  return v >= 0.f ? v : kNegSlope * v;
}
// online softmax accumulate (masked stream)
__device__ __forceinline__ void onl(float& m, float& l, float v) {
  if (v > m) { l = l * __expf(m - v) + 1.f; m = v; }
  else       { l += __expf(v - m); }
}
__device__ __forceinline__ void mergeml(float& M, float& L, float m, float l) {
  if (m > M) { L = L * __expf(M - m) + l; M = m; }
  else       { L += l * __expf(m - M); }
}

// ---------------- adjacency bitsets ----------------
__global__ void build_bits(const int* __restrict__ ei, int E,
                           unsigned long long* rowbits, unsigned long long* colbitsT) {
  int e = blockIdx.x * 256 + threadIdx.x;
  if (e >= E) return;
  int s = ei[e], d = ei[E + e];
  atomicOr(&rowbits[(size_t)s * kWords + (d >> 6)], 1ull << (d & 63));
  atomicOr(&colbitsT[(size_t)(s >> 6) * kN + d], 1ull << (s & 63));
}

// Fused per-row: A2 row s (counts via scatter) -> A2 structure (colbits2T)
// -> A3 row s = sum_k A2[s][k] * rowA[k] (via scatter) -> normalized motif.
// One block per s.
__global__ __launch_bounds__(256) void a3_motif(
    const unsigned long long* __restrict__ rowbits,
    float* __restrict__ motif,
    unsigned long long* __restrict__ colbits2T) {
  int s = blockIdx.x;
  int t = threadIdx.x;
  int lane = t & 63;
  __shared__ int cnt[kN];             // A2[s][k] counts (8 KB)
  __shared__ int sums[kN];            // A3[s][d] accumulators (8 KB)
  __shared__ unsigned short list[kN]; // jlist (phase1) then klist (phase3)
  __shared__ int n_total;
  __shared__ float redv[4];
  // zero cnt and sums
  reinterpret_cast<uint4*>(cnt)[t] = make_uint4(0u, 0u, 0u, 0u);
  reinterpret_cast<uint4*>(cnt)[t + 256] = make_uint4(0u, 0u, 0u, 0u);
  reinterpret_cast<uint4*>(sums)[t] = make_uint4(0u, 0u, 0u, 0u);
  reinterpret_cast<uint4*>(sums)[t + 256] = make_uint4(0u, 0u, 0u, 0u);
  __syncthreads();
  // decode out-neighbors j of s (wave 0) into list
  if (t < 64) {
    unsigned long long word = (lane < kWords) ? rowbits[(size_t)s * kWords + lane] : 0ull;
    int c = __popcll(word);
    int inc = c;
    for (int o = 1; o < 64; o <<= 1) { int v = __shfl_up(inc, o); if (lane >= o) inc += v; }
    if (lane == 63) n_total = inc;
    int off = inc - c;
    int base = lane * 64;
    while (word) {
      int b = __builtin_ctzll(word);
      word &= word - 1;
      list[off++] = (unsigned short)(base + b);
    }
  }
  __syncthreads();
  int jtot = n_total;
  // phase 1: cnt[k] += 1 for each j in rowA[s], k in rowA[j]  (flat scatter)
  for (int idx = t; idx < jtot * kWords; idx += 256) {
    int j = list[idx >> 5];
    int w = idx & (kWords - 1);
    unsigned long long word = rowbits[(size_t)j * kWords + w];
    int base = w * 64;
    while (word) {
      int b = __builtin_ctzll(word);
      word &= word - 1;
      atomicAdd(&cnt[base + b], 1);
    }
  }
  __syncthreads();
  // phase 2: klist = {k: cnt[k] > 0}; also write A2 structure bit (s, k)
  if (t < 64) {
    int base = lane * 32;
    unsigned int m = 0;
#pragma unroll
    for (int i = 0; i < 32; ++i) m |= (cnt[base + i] != 0 ? 1u : 0u) << i;
    int c = __popc(m);
    int inc = c;
    for (int o = 1; o < 64; o <<= 1) { int v = __shfl_up(inc, o); if (lane >= o) inc += v; }
    if (lane == 63) n_total = inc;
    int off = inc - c;
    unsigned int mm = m;
    while (mm) {
      int b = __builtin_ctz(mm);
      mm &= mm - 1;
      int k = base + b;
      list[off++] = (unsigned short)k;
      atomicOr(&colbits2T[(size_t)(s >> 6) * kN + k], 1ull << (s & 63));
    }
  }
  __syncthreads();
  int ktot = n_total;
  // phase 3: sums[d] += cnt[k] for each k in klist, d in rowA[k]  (flat scatter)
  for (int idx = t; idx < ktot * kWords; idx += 256) {
    int k = list[idx >> 5];
    int w = idx & (kWords - 1);
    unsigned long long word = rowbits[(size_t)k * kWords + w];
    int ck = cnt[k];
    int base = w * 64;
    while (word) {
      int b = __builtin_ctzll(word);
      word &= word - 1;
      atomicAdd(&sums[base + b], ck);
    }
  }
  __syncthreads();
  // phase 4: reduce row total, normalize, write motif row
  float tot = 0.f;
  int sv[8];
#pragma unroll
  for (int c = 0; c < 8; ++c) { sv[c] = sums[t + c * 256]; tot += (float)sv[c]; }
  for (int o = 32; o; o >>= 1) tot += __shfl_xor(tot, o);
  if (lane == 0) redv[t >> 6] = tot;
  __syncthreads();
  float inv = 1.f / fmaxf(redv[0] + redv[1] + redv[2] + redv[3], 1.f);
#pragma unroll
  for (int c = 0; c < 8; ++c)
    motif[(size_t)s * kN + t + c * 256] = (float)sv[c] * inv;
}

// C[z][M,Nn] = A[M,K] @ B_z[K,Nn]; B_z = z<nmain ? Bmain+z*K*Nn : Bx
__global__ __launch_bounds__(256) void gemm_batched(
    const float* __restrict__ A, const float* __restrict__ Bmain,
    const float* __restrict__ Bx, float* __restrict__ C,
    int M, int Nn, int K, int nmain) {
  int z = blockIdx.z;
  const float* B = (z < nmain) ? Bmain + (size_t)z * K * Nn : Bx;
  float* Cz = C + (size_t)z * M * Nn;
  __shared__ float As[16][65];
  __shared__ float Bs[16][65];
  int t = threadIdx.x;
  int tx = t & 15, ty = t >> 4;
  int row0 = blockIdx.y * 64, col0 = blockIdx.x * 64;
  float acc[4][4] = {};
  for (int k0 = 0; k0 < K; k0 += 16) {
    {
      int e = t * 4;
      int m = e >> 4, kk = e & 15;
      float4 va = *reinterpret_cast<const float4*>(A + (size_t)(row0 + m) * K + k0 + kk);
      As[kk + 0][m] = va.x; As[kk + 1][m] = va.y;
      As[kk + 2][m] = va.z; As[kk + 3][m] = va.w;
    }
    {
      int kb = t >> 4, nb = (t & 15) * 4;
      float4 vb = *reinterpret_cast<const float4*>(B + (size_t)(k0 + kb) * Nn + col0 + nb);
      Bs[kb][nb + 0] = vb.x; Bs[kb][nb + 1] = vb.y;
      Bs[kb][nb + 2] = vb.z; Bs[kb][nb + 3] = vb.w;
    }
    __syncthreads();
#pragma unroll
    for (int kk2 = 0; kk2 < 16; ++kk2) {
      float a[4], b[4];
#pragma unroll
      for (int i = 0; i < 4; ++i) a[i] = As[kk2][ty * 4 + i];
#pragma unroll
      for (int j = 0; j < 4; ++j) b[j] = Bs[kk2][tx * 4 + j];
#pragma unroll
      for (int i = 0; i < 4; ++i)
#pragma unroll
        for (int j = 0; j < 4; ++j) acc[i][j] += a[i] * b[j];
    }
    __syncthreads();
  }
  for (int i = 0; i < 4; ++i)
    for (int j = 0; j < 4; ++j)
      Cz[(size_t)(row0 + ty * 4 + i) * Nn + col0 + tx * 4 + j] = acc[i][j];
}

// s_src[hop,n,h], s_dst[hop,n,h]; block = H*64 threads; grid (N, 2)
template <int H>
__global__ void src_dst(const float* __restrict__ hopx,
                        const float* __restrict__ att_s,
                        const float* __restrict__ att_d,
                        float* __restrict__ ssrc, float* __restrict__ sdst) {
  int hop = blockIdx.y;
  int n = blockIdx.x;
  int t = threadIdx.x;
  int hh = t >> 6, c = t & 63;
  float xv = hopx[((size_t)hop * kN + n) * (H * 64) + t];
  float ps = xv * att_s[hop * H * 64 + hh * 64 + c];
  float pd = xv * att_d[hop * H * 64 + hh * 64 + c];
  for (int o = 32; o; o >>= 1) { ps += __shfl_xor(ps, o); pd += __shfl_xor(pd, o); }
  if (c == 0) {
    ssrc[((size_t)hop * kN + n) * H + hh] = ps;
    sdst[((size_t)hop * kN + n) * H + hh] = pd;
  }
}

// per (d,h): online-softmax stats over set bits of column mask.
// One wave per dst; lane l owns half of word l>>1. block 256; grid (N/4, 2)
template <int H>
__global__ __launch_bounds__(256) void stats_bits(
    const float* __restrict__ ssrc, const float* __restrict__ sdst,
    const float* __restrict__ motif,
    const unsigned long long* __restrict__ colbitsT,
    const unsigned long long* __restrict__ colbits2T,
    float* __restrict__ stats) {
  int hop = blockIdx.y;
  const unsigned long long* colmaskT = hop ? colbits2T : colbitsT;
  ssrc += (size_t)hop * kN * H;
  sdst += (size_t)hop * kN * H;
  stats += (size_t)hop * kN * H * 4;
  int wave = threadIdx.x >> 6, lane = threadIdx.x & 63;
  int d = blockIdx.x * 4 + wave;
  int w = lane >> 1, half = lane & 1;
  unsigned long long word = colmaskT[(size_t)w * kN + d];
  if (w == (d >> 6)) word |= 1ull << (d & 63);  // diagonal always masked-in
  unsigned int bits = (unsigned int)(word >> (half * 32));
  float sd[H];
#pragma unroll
  for (int h = 0; h < H; ++h) sd[h] = sdst[d * H + h];
  float m1[H], l1[H], m2[H], l2[H];
#pragma unroll
  for (int h = 0; h < H; ++h) { m1[h] = m2[h] = -3.0e38f; l1[h] = l2[h] = 0.f; }
  int base = w * 64 + half * 32;
  while (bits) {
    int b = __builtin_ctz(bits);
    bits &= bits - 1;
    int s = base + b;
    float mv = motif[(size_t)s * kN + d];
#pragma unroll
    for (int h = 0; h < H; ++h) {
      float v = ssrc[s * H + h] + sd[h];
      onl(m1[h], l1[h], leakyf(v));
      onl(m2[h], l2[h], leakyf(v * mv));
    }
  }
#pragma unroll
  for (int o = 1; o < 64; o <<= 1) {
#pragma unroll
    for (int h = 0; h < H; ++h) {
      float mm = __shfl_xor(m1[h], o), ll = __shfl_xor(l1[h], o);
      mergeml(m1[h], l1[h], mm, ll);
      float mm2 = __shfl_xor(m2[h], o), ll2 = __shfl_xor(l2[h], o);
      mergeml(m2[h], l2[h], mm2, ll2);
    }
  }
  if (lane == 0) {
#pragma unroll
    for (int h = 0; h < H; ++h) {
      float* sp = stats + ((size_t)d * H + h) * 4;
      sp[0] = m1[h]; sp[1] = 1.f / l1[h]; sp[2] = m2[h]; sp[3] = 1.f / l2[h];
    }
  }
}

// layer-1 aggregation: one dst per block (256 thr = 256 channels), both hops,
// sparse s-list from bitsets; fused bias + ELU. grid = N.
__global__ __launch_bounds__(256) void agg_l1(
    const float* __restrict__ hx,      // [2][N][256]
    const float* __restrict__ ssrc,    // [2][N][4]
    const float* __restrict__ sdst,    // [2][N][4]
    const float* __restrict__ motif,
    const unsigned long long* __restrict__ colbitsT,
    const unsigned long long* __restrict__ colbits2T,
    const float* __restrict__ stats,   // [2][N][4][4]
    const float* __restrict__ hop_att,
    const float* __restrict__ bias,
    float* __restrict__ hbuf) {
  int d = blockIdx.x;
  int t = threadIdx.x;
  int lane = t & 63;
  int h = t >> 6;
  __shared__ unsigned short slist[kN];
  __shared__ float w_lds[64 * 4];
  __shared__ int s_total;
  float a0 = hop_att[0], a1 = hop_att[1];
  float mxa = fmaxf(a0, a1);
  float e0 = __expf(a0 - mxa), e1 = __expf(a1 - mxa);
  float wh0 = e0 / (e0 + e1), wh1 = e1 / (e0 + e1);
  float acc = 0.f;
  for (int hop = 0; hop < 2; ++hop) {
    const unsigned long long* cm = hop ? colbits2T : colbitsT;
    if (t < 64) {
      unsigned long long word = (lane < kWords) ? cm[(size_t)lane * kN + d] : 0ull;
      if (lane == (d >> 6)) word |= 1ull << (d & 63);
      int cnt = __popcll(word);
      int inc = cnt;
      for (int o = 1; o < 64; o <<= 1) { int v = __shfl_up(inc, o); if (lane >= o) inc += v; }
      if (lane == 63) s_total = inc;
      int off = inc - cnt;
      int base = lane * 64;
      while (word) {
        int b = __builtin_ctzll(word);
        word &= word - 1;
        slist[off++] = (unsigned short)(base + b);
      }
    }
    __syncthreads();
    int total = s_total;
    float sd = sdst[((size_t)hop * kN + d) * 4 + h];
    const float* sp = &stats[(((size_t)hop * kN + d) * 4 + h) * 4];
    float m1 = sp[0], il1 = sp[1], m2 = sp[2], il2 = sp[3];
    float wh = hop ? wh1 : wh0;
    const float* hxp = hx + (size_t)hop * kN * kC1;
    const float* ssp = ssrc + (size_t)hop * kN * 4;
    for (int c0 = 0; c0 < total; c0 += 64) {
      int nsi = min(64, total - c0);
      int si = lane;
      if (si < nsi) {
        int s = slist[c0 + si];
        float mv = motif[(size_t)s * kN + d];
        float v = ssp[s * 4 + h] + sd;
        w_lds[si * 4 + h] = (0.5f * __expf(leakyf(v) - m1) * il1 +
                             0.5f * __expf(leakyf(v * mv) - m2) * il2) * wh;
      }
      __syncthreads();
      for (int q = 0; q < nsi; ++q) {
        int s = slist[c0 + q];
        acc += w_lds[q * 4 + h] * hxp[(size_t)s * kC1 + t];
      }
      __syncthreads();
    }
    __syncthreads();
  }
  acc += bias[t];
  hbuf[(size_t)d * kC1 + t] = acc > 0.f ? acc : __expf(acc) - 1.f;
}

// layer-2 aggregation: one dst per block, 4 si-subgroups x 64 channels;
// fused residual + LayerNorm + bias -> final output. grid = N.
__global__ __launch_bounds__(256) void agg_l2(
    const float* __restrict__ hx,      // [2][N][64]
    const float* __restrict__ ssrc,    // [2][N]
    const float* __restrict__ sdst,    // [2][N]
    const float* __restrict__ motif,
    const unsigned long long* __restrict__ colbitsT,
    const unsigned long long* __restrict__ colbits2T,
    const float* __restrict__ stats,   // [2][N][4]
    const float* __restrict__ hop_att,
    const float* __restrict__ res,     // [N][64]
    const float* __restrict__ lns, const float* __restrict__ lnb,
    const float* __restrict__ l2b,
    float* __restrict__ out) {
  int d = blockIdx.x;
  int t = threadIdx.x;
  int lane = t & 63;   // channel
  int g = t >> 6;      // si-subgroup
  __shared__ unsigned short slist[kN];
  __shared__ float w_lds[64];
  __shared__ int s_total;
  __shared__ float red[4][64];
  float a0 = hop_att[0], a1 = hop_att[1];
  float mxa = fmaxf(a0, a1);
  float e0 = __expf(a0 - mxa), e1 = __expf(a1 - mxa);
  float wh0 = e0 / (e0 + e1), wh1 = e1 / (e0 + e1);
  float acc = 0.f;
  for (int hop = 0; hop < 2; ++hop) {
    const unsigned long long* cm = hop ? colbits2T : colbitsT;
    if (t < 64) {
      unsigned long long word = (lane < kWords) ? cm[(size_t)lane * kN + d] : 0ull;
      if (lane == (d >> 6)) word |= 1ull << (d & 63);
      int cnt = __popcll(word);
      int inc = cnt;
      for (int o = 1; o < 64; o <<= 1) { int v = __shfl_up(inc, o); if (lane >= o) inc += v; }
      if (lane == 63) s_total = inc;
      int off = inc - cnt;
      int base = lane * 64;
      while (word) {
        int b = __builtin_ctzll(word);
        word &= word - 1;
        slist[off++] = (unsigned short)(base + b);
      }
    }
    __syncthreads();
    int total = s_total;
    float sd = sdst[(size_t)hop * kN + d];
    const float* sp = &stats[((size_t)hop * kN + d) * 4];
    float m1 = sp[0], il1 = sp[1], m2 = sp[2], il2 = sp[3];
    float wh = hop ? wh1 : wh0;
    const float* hxp = hx + (size_t)hop * kN * kC2;
    const float* ssp = ssrc + (size_t)hop * kN;
    for (int c0 = 0; c0 < total; c0 += 64) {
      int nsi = min(64, total - c0);
      if (t < nsi) {
        int s = slist[c0 + t];
        float mv = motif[(size_t)s * kN + d];
        float v = ssp[s] + sd;
        w_lds[t] = (0.5f * __expf(leakyf(v) - m1) * il1 +
                    0.5f * __expf(leakyf(v * mv) - m2) * il2) * wh;
      }
      __syncthreads();
      for (int q = g; q < nsi; q += 4) {
        int s = slist[c0 + q];
        acc += w_lds[q] * hxp[(size_t)s * kC2 + lane];
      }
      __syncthreads();
    }
    __syncthreads();
  }
  red[g][lane] = acc;
  __syncthreads();
  if (t < 64) {
    float v = red[0][t] + red[1][t] + red[2][t] + red[3][t] + res[(size_t)d * kC2 + t];
    float s = v;
    for (int o = 32; o; o >>= 1) s += __shfl_xor(s, o);
    float mu = s * (1.f / kC2);
    float dv = v - mu;
    float q = dv * dv;
    for (int o = 32; o; o >>= 1) q += __shfl_xor(q, o);
    float var = q * (1.f / kC2);
    out[(size_t)d * kC2 + t] = dv * rsqrtf(var + kLnEps) * lns[t] + lnb[t] + l2b[t];
  }
}

}  // namespace

extern "C" void kernel_launch(void* const* d_in, const int* in_sizes, int n_in,
                              void* d_out, int out_size, void* d_ws, size_t ws_size,
                              hipStream_t stream) {
  const float* x    = (const float*)d_in[0];
  const int*   ei   = (const int*)d_in[1];
  const float* l1w  = (const float*)d_in[2];
  const float* l1as = (const float*)d_in[3];
  const float* l1ad = (const float*)d_in[4];
  const float* l1ha = (const float*)d_in[5];
  const float* l1b  = (const float*)d_in[6];
  const float* l2w  = (const float*)d_in[7];
  const float* l2as = (const float*)d_in[8];
  const float* l2ad = (const float*)d_in[9];
  const float* l2ha = (const float*)d_in[10];
  const float* l2rw = (const float*)d_in[11];
  const float* lns  = (const float*)d_in[12];
  const float* lnb  = (const float*)d_in[13];
  const float* l2b  = (const float*)d_in[14];
  int E = in_sizes[1] / 2;

  // ---- workspace layout (bytes) ----
  size_t o = 0;
  auto take = [&](size_t bytes) { size_t r = o; o += (bytes + 255) & ~(size_t)255; return r; };
  size_t oRB  = take((size_t)kN * kWords * 8);      // rowbits
  size_t oCB  = take((size_t)kWords * kN * 8);      // colbitsT
  size_t oCB2 = take((size_t)kWords * kN * 8);      // colbits2T (A2 structure)
  size_t zEnd = o;                                  // zero region end
  size_t oMF  = take((size_t)kN * kN * 4);
  size_t oHX1 = take((size_t)2 * kN * kC1 * 4);
  size_t oH   = take((size_t)kN * kC1 * 4);
  size_t oHX2 = take((size_t)3 * kN * kC2 * 4);     // hop0 | hop1 | res
  size_t oSS1 = take((size_t)2 * kN * 4 * 4);
  size_t oSD1 = take((size_t)2 * kN * 4 * 4);
  size_t oSS2 = take((size_t)2 * kN * 4);
  size_t oSD2 = take((size_t)2 * kN * 4);
  size_t oST1 = take((size_t)2 * kN * 4 * 4 * 4);
  size_t oST2 = take((size_t)2 * kN * 4 * 4);
  if (ws_size < o) return;  // insufficient scratch; fail visibly

  char* w = (char*)d_ws;
  unsigned long long* rowbits = (unsigned long long*)(w + oRB);
  unsigned long long* colbitsT = (unsigned long long*)(w + oCB);
  unsigned long long* colbits2T = (unsigned long long*)(w + oCB2);
  float* motif = (float*)(w + oMF);
  float* hx1 = (float*)(w + oHX1);
  float* hbuf = (float*)(w + oH);
  float* hx2 = (float*)(w + oHX2);
  float* res = hx2 + (size_t)2 * kN * kC2;
  float* ss1 = (float*)(w + oSS1);
  float* sd1 = (float*)(w + oSD1);
  float* ss2 = (float*)(w + oSS2);
  float* sd2 = (float*)(w + oSD2);
  float* st1 = (float*)(w + oST1);
  float* st2 = (float*)(w + oST2);

  hipMemsetAsync(d_ws, 0, zEnd, stream);

  build_bits<<<(E + 255) / 256, 256, 0, stream>>>(ei, E, rowbits, colbitsT);
  a3_motif<<<kN, 256, 0, stream>>>(rowbits, motif, colbits2T);

  // ---- layer 1 (H=4, C=64, concat) ----
  gemm_batched<<<dim3(kC1 / 64, kN / 64, 2), 256, 0, stream>>>(
      x, l1w, l1w, hx1, kN, kC1, kIN, 2);
  src_dst<4><<<dim3(kN, 2), 256, 0, stream>>>(hx1, l1as, l1ad, ss1, sd1);
  stats_bits<4><<<dim3(kN / 4, 2), 256, 0, stream>>>(
      ss1, sd1, motif, colbitsT, colbits2T, st1);
  agg_l1<<<kN, 256, 0, stream>>>(hx1, ss1, sd1, motif, colbitsT, colbits2T,
                                 st1, l1ha, l1b, hbuf);

  // ---- layer 2 (H=1, C=64, residual + LN) ----
  gemm_batched<<<dim3(1, kN / 64, 3), 256, 0, stream>>>(
      hbuf, l2w, l2rw, hx2, kN, kC2, kC1, 2);
  src_dst<1><<<dim3(kN, 2), 64, 0, stream>>>(hx2, l2as, l2ad, ss2, sd2);
  stats_bits<1><<<dim3(kN / 4, 2), 256, 0, stream>>>(
      ss2, sd2, motif, colbitsT, colbits2T, st2);
  agg_l2<<<kN, 256, 0, stream>>>(hx2, ss2, sd2, motif, colbitsT, colbits2T,
                                 st2, l2ha, res, lns, lnb, l2b, (float*)d_out);
}